// Round 1
// baseline (145.828 us; speedup 1.0000x reference)
//
#include <hip/hip_runtime.h>

#define NBATCH 4
#define DDIM   256
#define NN     4096
#define MM     4096
#define NCHUNK 8          // m-chunks (split-K across workgroups)
#define MCHUNK 512        // m per chunk
#define MTILE  32         // m per LDS tile
#define LOG2E  1.44269504088896340736f

using half8  = __attribute__((ext_vector_type(8))) _Float16;
using floatx4 = __attribute__((ext_vector_type(4))) float;

// ---------------- transpose + fp32->fp16 convert:  emb[b][d][n] -> Xh[b][n][d] ----------------
__global__ __launch_bounds__(256) void k_transpose(const float* __restrict__ src_emb,
                                                   const float* __restrict__ tgt_emb,
                                                   _Float16* __restrict__ Qh,
                                                   _Float16* __restrict__ Kh) {
    __shared__ float tile[64][65];                 // +1 pad: conflict-free transpose
    int bz = blockIdx.z;                           // tensor*4 + b
    int tensor = bz >> 2, b = bz & 3;
    const float* in = tensor ? tgt_emb : src_emb;
    _Float16* out   = tensor ? Kh : Qh;
    int n0 = blockIdx.x * 64, d0 = blockIdx.y * 64;
    int t = threadIdx.x;
    int c = t & 63, r0 = t >> 6;
    const float* ip = in + (size_t)(b * DDIM + d0) * NN + n0 + c;   // c = n-offset
#pragma unroll
    for (int i = 0; i < 16; i++) {
        int r = r0 + i * 4;                        // r = d-offset
        tile[r][c] = ip[(size_t)r * NN];
    }
    __syncthreads();
    _Float16* op = out + (size_t)(b * NN + n0) * DDIM + d0 + c;     // c = d-offset now
#pragma unroll
    for (int i = 0; i < 16; i++) {
        int r = r0 + i * 4;                        // r = n-offset
        op[(size_t)r * DDIM] = (_Float16)tile[c][r];
    }
}

// ---------------- yy[b][m] = -log2e * sum_d tgt_emb^2 ;  Vt[b][m] = {v0,v1,v2,1} ----------------
__global__ __launch_bounds__(256) void k_yyvt(const float* __restrict__ tgt,
                                              const float* __restrict__ tgt_emb,
                                              float* __restrict__ yy,
                                              float4* __restrict__ Vt) {
    int b = blockIdx.y;
    int m = blockIdx.x * 256 + threadIdx.x;
    const float* p = tgt_emb + (size_t)b * DDIM * MM + m;
    float s = 0.f;
#pragma unroll 8
    for (int d = 0; d < DDIM; d++) { float v = p[(size_t)d * MM]; s = fmaf(v, v, s); }
    yy[b * MM + m] = s * (-LOG2E);                 // pre-negated, pre-scaled to log2 domain
    const float* tp = tgt + (size_t)b * 3 * MM + m;
    Vt[b * MM + m] = make_float4(tp[0], tp[MM], tp[2 * MM], 1.0f);  // .w=1 accumulates softmax denom
}

// ---------------- fused flash kernel: per wave 64n x (chunk of 512 m), D=256 ----------------
__global__ __launch_bounds__(256, 2) void k_flash(const _Float16* __restrict__ Qh,
                                                  const _Float16* __restrict__ Kh,
                                                  const float* __restrict__ yy,
                                                  const float4* __restrict__ Vt,
                                                  float4* __restrict__ Opart,
                                                  float* __restrict__ Mpart) {
    __shared__ half8   Kt8[MTILE * 33];            // 32 rows x (256+8 pad) f16, 16B aligned
    __shared__ floatx4 yyt4[MTILE / 4];
    __shared__ float4  vtt[MTILE];

    // XCD-aware decode: each XCD works on few (b,chunk) Kh slices -> L2 locality
    int i = blockIdx.x;
    int xcd = i & 7, s = i >> 3;
    int grp = xcd + 8 * (s >> 4);                  // [0,32)
    int b = grp >> 3, chunk = grp & 7, ntile = s & 15;

    int t = threadIdx.x, wave = t >> 6, lane = t & 63, quad = lane >> 4, l15 = lane & 15;
    int n0 = ntile * 256 + wave * 64;

    // persistent Q fragments: 64 n x 256 d per wave, in registers (128 VGPRs)
    const half8* qp = (const half8*)Qh + (size_t)b * NN * 32;
    half8 qf[4][8];
#pragma unroll
    for (int nb = 0; nb < 4; nb++) {
        int n = n0 + nb * 16 + l15;
#pragma unroll
        for (int ds = 0; ds < 8; ds++) qf[nb][ds] = qp[n * 32 + ds * 4 + quad];
    }

    const floatx4 z4 = {0.f, 0.f, 0.f, 0.f};
    floatx4 o[4] = {z4, z4, z4, z4};               // {o0,o1,o2,l} per owned row group
    float mr[4] = {-__builtin_inff(), -__builtin_inff(), -__builtin_inff(), -__builtin_inff()};

    const half8* kp = (const half8*)Kh + (size_t)b * MM * 32;
    int m0 = chunk * MCHUNK;
    int srow = t >> 5, sdc = t & 31;               // staging decomposition

    for (int mt = 0; mt < MCHUNK / MTILE; mt++) {
        int mg = m0 + mt * MTILE;
        __syncthreads();
        // stage K-tile (32 x 256 f16), yy tile, V tile
#pragma unroll
        for (int it = 0; it < 4; it++) {
            int mrow = srow + it * 8;
            Kt8[mrow * 33 + sdc] = kp[(size_t)(mg + mrow) * 32 + sdc];
        }
        if (t < MTILE / 4) yyt4[t] = ((const floatx4*)(yy + b * MM + mg))[t];
        else if (t >= 64 && t < 64 + MTILE) vtt[t - 64] = Vt[b * MM + mg + (t - 64)];
        __syncthreads();

        // QK^T: D[i=m][j=n], A = K-tile (LDS, reused x4), B = Q (registers)
        floatx4 acc[4][2];
#pragma unroll
        for (int nb = 0; nb < 4; nb++) { acc[nb][0] = z4; acc[nb][1] = z4; }
#pragma unroll
        for (int ds = 0; ds < 8; ds++) {
            half8 a0 = Kt8[l15 * 33 + ds * 4 + quad];
            half8 a1 = Kt8[(16 + l15) * 33 + ds * 4 + quad];
#pragma unroll
            for (int nb = 0; nb < 4; nb++) {
                acc[nb][0] = __builtin_amdgcn_mfma_f32_16x16x32_f16(a0, qf[nb][ds], acc[nb][0], 0, 0, 0);
                acc[nb][1] = __builtin_amdgcn_mfma_f32_16x16x32_f16(a1, qf[nb][ds], acc[nb][1], 0, 0, 0);
            }
        }

        // online softmax (log2 domain) + PV accumulate; lane owns n = n0+nb*16+l15
        floatx4 yv0 = yyt4[quad], yv1 = yyt4[4 + quad];
#pragma unroll
        for (int nb = 0; nb < 4; nb++) {
            float sv[8];
#pragma unroll
            for (int r = 0; r < 4; r++) {
                sv[r]     = fmaf(acc[nb][0][r], 2.f * LOG2E, yv0[r]);   // m = quad*4+r
                sv[4 + r] = fmaf(acc[nb][1][r], 2.f * LOG2E, yv1[r]);   // m = 16+quad*4+r
            }
            float tm = sv[0];
#pragma unroll
            for (int r = 1; r < 8; r++) tm = fmaxf(tm, sv[r]);
            tm = fmaxf(tm, __shfl_xor(tm, 16, 64));                     // max across quads
            tm = fmaxf(tm, __shfl_xor(tm, 32, 64));
            float mnew  = fmaxf(mr[nb], tm);
            float alpha = __builtin_amdgcn_exp2f(mr[nb] - mnew);        // first tile: exp2(-inf)=0
            mr[nb] = mnew;
            floatx4 oa = o[nb] * alpha;
#pragma unroll
            for (int mb = 0; mb < 2; mb++) {
#pragma unroll
                for (int r = 0; r < 4; r++) {
                    float p = __builtin_amdgcn_exp2f(sv[mb * 4 + r] - mnew);
                    float4 v = vtt[mb * 16 + quad * 4 + r];             // broadcast within quad
                    oa[0] = fmaf(p, v.x, oa[0]);
                    oa[1] = fmaf(p, v.y, oa[1]);
                    oa[2] = fmaf(p, v.z, oa[2]);
                    oa[3] = fmaf(p, v.w, oa[3]);                        // denom (v.w == 1)
                }
            }
            o[nb] = oa;
        }
    }

    // reduce partial sums across quads (each quad covered different m's; mr identical across quads)
#pragma unroll
    for (int nb = 0; nb < 4; nb++) {
#pragma unroll
        for (int c = 0; c < 4; c++) {
            float v = o[nb][c];
            v += __shfl_xor(v, 16, 64);
            v += __shfl_xor(v, 32, 64);
            o[nb][c] = v;
        }
    }
    if (quad == 0) {
#pragma unroll
        for (int nb = 0; nb < 4; nb++) {
            int n = n0 + nb * 16 + l15;
            size_t idx = (size_t)(chunk * NBATCH + b) * NN + n;
            Opart[idx] = make_float4(o[nb][0], o[nb][1], o[nb][2], o[nb][3]);
            Mpart[idx] = mr[nb];
        }
    }
}

// ---------------- combine the 8 m-chunk partials per (b,n) ----------------
__global__ __launch_bounds__(256) void k_combine(const float4* __restrict__ Opart,
                                                 const float* __restrict__ Mpart,
                                                 float* __restrict__ out) {
    int idx = blockIdx.x * 256 + threadIdx.x;      // b*NN + n
    int b = idx >> 12, n = idx & (NN - 1);
    float mstar = -__builtin_inff();
#pragma unroll
    for (int j = 0; j < NCHUNK; j++)
        mstar = fmaxf(mstar, Mpart[(size_t)(j * NBATCH + b) * NN + n]);
    float o0 = 0.f, o1 = 0.f, o2 = 0.f, l = 0.f;
#pragma unroll
    for (int j = 0; j < NCHUNK; j++) {
        size_t id = (size_t)(j * NBATCH + b) * NN + n;
        float w = __builtin_amdgcn_exp2f(Mpart[id] - mstar);
        float4 P = Opart[id];
        o0 = fmaf(w, P.x, o0); o1 = fmaf(w, P.y, o1);
        o2 = fmaf(w, P.z, o2); l  = fmaf(w, P.w, l);
    }
    out[(size_t)(b * 3 + 0) * NN + n] = o0 / l;
    out[(size_t)(b * 3 + 1) * NN + n] = o1 / l;
    out[(size_t)(b * 3 + 2) * NN + n] = o2 / l;
}

extern "C" void kernel_launch(void* const* d_in, const int* in_sizes, int n_in,
                              void* d_out, int out_size, void* d_ws, size_t ws_size,
                              hipStream_t stream) {
    const float* tgt     = (const float*)d_in[1];
    const float* src_emb = (const float*)d_in[2];
    const float* tgt_emb = (const float*)d_in[3];
    float* out = (float*)d_out;

    char* ws = (char*)d_ws;
    // ws layout (bytes): Qh 8.39M | Kh 8.39M | yy 64K | Vt 256K | Opart 2M | Mpart 512K  (~19.7 MB)
    _Float16* Qh   = (_Float16*)(ws);
    _Float16* Kh   = (_Float16*)(ws + 8388608);
    float*    yy   = (float*)   (ws + 16777216);
    float4*   Vt   = (float4*)  (ws + 16842752);
    float4*   Op   = (float4*)  (ws + 17104896);
    float*    Mp   = (float*)   (ws + 19202048);

    hipLaunchKernelGGL(k_transpose, dim3(64, 4, 8), dim3(256), 0, stream, src_emb, tgt_emb, Qh, Kh);
    hipLaunchKernelGGL(k_yyvt,      dim3(16, 4),    dim3(256), 0, stream, tgt, tgt_emb, yy, Vt);
    hipLaunchKernelGGL(k_flash,     dim3(512),      dim3(256), 0, stream, Qh, Kh, yy, Vt, Op, Mp);
    hipLaunchKernelGGL(k_combine,   dim3(64),       dim3(256), 0, stream, Op, Mp, out);
}

// Round 2
// 141.467 us; speedup vs baseline: 1.0308x; 1.0308x over previous
//
#include <hip/hip_runtime.h>

#define NBATCH 4
#define DDIM   256
#define NN     4096
#define MM     4096
#define NCHUNK 8          // m-chunks (split-K across workgroups)
#define MCHUNK 512        // m per chunk
#define MTILE  64         // m per LDS tile
#define LOG2E  1.44269504088896340736f

using half8   = __attribute__((ext_vector_type(8))) _Float16;
using floatx4 = __attribute__((ext_vector_type(4))) float;

// ---------- transpose + fp32->fp16:  emb[b][d][n] -> Xh[b][n][d]; Q pre-scaled by 2*log2e ----------
__global__ __launch_bounds__(256) void k_prep(const float* __restrict__ src_emb,
                                              const float* __restrict__ tgt_emb,
                                              _Float16* __restrict__ Qh,
                                              _Float16* __restrict__ Kh) {
    __shared__ float tile[64][65];                 // [d][n], +1 pad
    int bz = blockIdx.z;                           // tensor*4 + b
    int tensor = bz >> 2, b = bz & 3;
    const float* in = tensor ? tgt_emb : src_emb;
    _Float16* out   = tensor ? Kh : Qh;
    const float scale = tensor ? 1.0f : 2.0f * LOG2E;   // fold softmax scale into Q
    int n0 = blockIdx.x * 64, d0 = blockIdx.y * 64;
    int t = threadIdx.x;
    {
        int c = t & 63, r0 = t >> 6;
        const float* ip = in + (size_t)(b * DDIM + d0) * NN + n0 + c;   // c = n
#pragma unroll
        for (int i = 0; i < 16; i++) {
            int r = r0 + i * 4;                    // r = d
            tile[r][c] = ip[(size_t)r * NN];
        }
    }
    __syncthreads();
    int dg = t & 7, nn = t >> 3;                   // dg: which 8-d group, nn: n within half-tile
#pragma unroll
    for (int pass = 0; pass < 2; pass++) {
        int n = nn + pass * 32;
        half8 h;
#pragma unroll
        for (int k = 0; k < 8; k++) h[k] = (_Float16)(tile[dg * 8 + k][n] * scale);
        *(half8*)(out + (size_t)(b * NN + n0 + n) * DDIM + d0 + dg * 8) = h;   // 16B/lane, coalesced
    }
}

// ---------- yy[b][m] = -log2e * sum_d Kh[b][m][d]^2  (reads fp16, d-contiguous) ----------
__global__ __launch_bounds__(256) void k_yy(const _Float16* __restrict__ Kh,
                                            float* __restrict__ yy) {
    int b = blockIdx.y;
    int m = blockIdx.x * 64 + (threadIdx.x >> 2);
    int j = threadIdx.x & 3;                       // 4 lanes per m
    const half8* p = (const half8*)(Kh + (size_t)(b * MM + m) * DDIM);
    float s = 0.f;
#pragma unroll
    for (int k = 0; k < 8; k++) {
        half8 v = p[k * 4 + j];                    // 4 lanes cover 64B contiguous
#pragma unroll
        for (int e = 0; e < 8; e++) { float f = (float)v[e]; s = fmaf(f, f, s); }
    }
    s += __shfl_xor(s, 1, 64);
    s += __shfl_xor(s, 2, 64);
    if (j == 0) yy[b * MM + m] = s * (-LOG2E);
}

// ---------- fused flash kernel: per wave 64n x (chunk of 512 m), D=256 ----------
__global__ __launch_bounds__(256, 2) void k_flash(const _Float16* __restrict__ Qh,
                                                  const _Float16* __restrict__ Kh,
                                                  const float* __restrict__ yy,
                                                  const float* __restrict__ tgt,
                                                  float4* __restrict__ Opart,
                                                  float* __restrict__ Mpart) {
    __shared__ half8   Kt8[MTILE * 33];            // 64 rows x (256+8 pad) f16
    __shared__ floatx4 yyt4[MTILE / 4];
    __shared__ floatx4 vtt[MTILE];                 // {v0,v1,v2,1}

    // XCD-aware decode
    int i = blockIdx.x;
    int xcd = i & 7, s = i >> 3;
    int grp = xcd + 8 * (s >> 4);                  // [0,32)
    int b = grp >> 3, chunk = grp & 7, ntile = s & 15;

    int t = threadIdx.x, wave = t >> 6, lane = t & 63, quad = lane >> 4, l15 = lane & 15;
    int n0 = ntile * 256 + wave * 64;

    // persistent Q fragments: 64 n x 256 d per wave (128 VGPRs)
    const half8* qp = (const half8*)Qh + (size_t)b * NN * 32;
    half8 qf[4][8];
#pragma unroll
    for (int nb = 0; nb < 4; nb++) {
        int n = n0 + nb * 16 + l15;
#pragma unroll
        for (int ds = 0; ds < 8; ds++) qf[nb][ds] = qp[n * 32 + ds * 4 + quad];
    }

    const floatx4 z4 = {0.f, 0.f, 0.f, 0.f};
    floatx4 o[4] = {z4, z4, z4, z4};               // {o0,o1,o2,denom}
    float mr[4] = {-__builtin_inff(), -__builtin_inff(), -__builtin_inff(), -__builtin_inff()};

    const half8* kp = (const half8*)Kh + (size_t)b * MM * 32;
    const float* tb = tgt + (size_t)b * 3 * MM;
    int m0 = chunk * MCHUNK;
    int srow = t >> 5, sdc = t & 31;

    for (int mt = 0; mt < MCHUNK / MTILE; mt++) {
        int mg = m0 + mt * MTILE;
        __syncthreads();
#pragma unroll
        for (int it = 0; it < 8; it++) {
            int mrow = srow + it * 8;
            Kt8[mrow * 33 + sdc] = kp[(size_t)(mg + mrow) * 32 + sdc];
        }
        if (t < MTILE) {                           // V gather straight from tgt (L2-hit)
            int m = mg + t;
            floatx4 v = {tb[m], tb[MM + m], tb[2 * MM + m], 1.0f};
            vtt[t] = v;
        } else if (t < MTILE + MTILE / 4) {
            yyt4[t - MTILE] = ((const floatx4*)(yy + b * MM + mg))[t - MTILE];
        }
        __syncthreads();

        // QK^T: D[i=m][j=n], A = K (LDS), B = Q (regs); lane owns col n = n0+nb*16+l15
        floatx4 acc[4][4];
#pragma unroll
        for (int nb = 0; nb < 4; nb++)
#pragma unroll
            for (int mb = 0; mb < 4; mb++) acc[nb][mb] = z4;
#pragma unroll
        for (int ds = 0; ds < 8; ds++) {
            half8 a[4];
#pragma unroll
            for (int mb = 0; mb < 4; mb++) a[mb] = Kt8[(mb * 16 + l15) * 33 + ds * 4 + quad];
#pragma unroll
            for (int nb = 0; nb < 4; nb++)
#pragma unroll
                for (int mb = 0; mb < 4; mb++)
                    acc[nb][mb] = __builtin_amdgcn_mfma_f32_16x16x32_f16(a[mb], qf[nb][ds], acc[nb][mb], 0, 0, 0);
        }

        // add yy (already -log2e scaled); Q carried 2*log2e, so acc+yv is the exp2-domain logit
#pragma unroll
        for (int mb = 0; mb < 4; mb++) {
            floatx4 yv = yyt4[mb * 4 + quad];
#pragma unroll
            for (int nb = 0; nb < 4; nb++) acc[nb][mb] = acc[nb][mb] + yv;
        }
        // online max / rescale per owned row n
#pragma unroll
        for (int nb = 0; nb < 4; nb++) {
            floatx4 mx = __builtin_elementwise_max(
                __builtin_elementwise_max(acc[nb][0], acc[nb][1]),
                __builtin_elementwise_max(acc[nb][2], acc[nb][3]));
            float tm = fmaxf(fmaxf(mx[0], mx[1]), fmaxf(mx[2], mx[3]));
            tm = fmaxf(tm, __shfl_xor(tm, 16, 64));
            tm = fmaxf(tm, __shfl_xor(tm, 32, 64));
            float mn = fmaxf(mr[nb], tm);
            float al = __builtin_amdgcn_exp2f(mr[nb] - mn);
            mr[nb] = mn;
            o[nb] = o[nb] * al;
            floatx4 mnv = {mn, mn, mn, mn};
#pragma unroll
            for (int mb = 0; mb < 4; mb++) acc[nb][mb] = acc[nb][mb] - mnv;
        }
        // exp + PV accumulate (vtt reads hoisted, reused across nb)
#pragma unroll
        for (int mb = 0; mb < 4; mb++) {
            floatx4 vr[4];
#pragma unroll
            for (int r = 0; r < 4; r++) vr[r] = vtt[mb * 16 + quad * 4 + r];
#pragma unroll
            for (int nb = 0; nb < 4; nb++)
#pragma unroll
                for (int r = 0; r < 4; r++) {
                    float p = __builtin_amdgcn_exp2f(acc[nb][mb][r]);
                    o[nb] = o[nb] + p * vr[r];     // floatx4 -> v_pk_fma_f32
                }
        }
    }

    // reduce partials across quads (each quad held different m rows; mr identical across quads)
#pragma unroll
    for (int nb = 0; nb < 4; nb++) {
#pragma unroll
        for (int c = 0; c < 4; c++) {
            float v = o[nb][c];
            v += __shfl_xor(v, 16, 64);
            v += __shfl_xor(v, 32, 64);
            o[nb][c] = v;
        }
    }
    if (quad == 0) {
#pragma unroll
        for (int nb = 0; nb < 4; nb++) {
            int n = n0 + nb * 16 + l15;
            size_t idx = (size_t)(chunk * NBATCH + b) * NN + n;
            Opart[idx] = make_float4(o[nb][0], o[nb][1], o[nb][2], o[nb][3]);
            Mpart[idx] = mr[nb];
        }
    }
}

// ---------- combine the 8 m-chunk partials per (b,n) ----------
__global__ __launch_bounds__(256) void k_combine(const float4* __restrict__ Opart,
                                                 const float* __restrict__ Mpart,
                                                 float* __restrict__ out) {
    int idx = blockIdx.x * 256 + threadIdx.x;      // b*NN + n
    int b = idx >> 12, n = idx & (NN - 1);
    float mstar = -__builtin_inff();
#pragma unroll
    for (int j = 0; j < NCHUNK; j++)
        mstar = fmaxf(mstar, Mpart[(size_t)(j * NBATCH + b) * NN + n]);
    float o0 = 0.f, o1 = 0.f, o2 = 0.f, l = 0.f;
#pragma unroll
    for (int j = 0; j < NCHUNK; j++) {
        size_t id = (size_t)(j * NBATCH + b) * NN + n;
        float w = __builtin_amdgcn_exp2f(Mpart[id] - mstar);
        float4 P = Opart[id];
        o0 = fmaf(w, P.x, o0); o1 = fmaf(w, P.y, o1);
        o2 = fmaf(w, P.z, o2); l  = fmaf(w, P.w, l);
    }
    out[(size_t)(b * 3 + 0) * NN + n] = o0 / l;
    out[(size_t)(b * 3 + 1) * NN + n] = o1 / l;
    out[(size_t)(b * 3 + 2) * NN + n] = o2 / l;
}

extern "C" void kernel_launch(void* const* d_in, const int* in_sizes, int n_in,
                              void* d_out, int out_size, void* d_ws, size_t ws_size,
                              hipStream_t stream) {
    const float* tgt     = (const float*)d_in[1];
    const float* src_emb = (const float*)d_in[2];
    const float* tgt_emb = (const float*)d_in[3];
    float* out = (float*)d_out;

    char* ws = (char*)d_ws;
    // ws layout (bytes): Qh 8.39M | Kh 8.39M | yy 64K | Opart 2M | Mpart 512K  (~19.5 MB)
    _Float16* Qh = (_Float16*)(ws);
    _Float16* Kh = (_Float16*)(ws + 8388608);
    float*    yy = (float*)   (ws + 16777216);
    float4*   Op = (float4*)  (ws + 16842752);
    float*    Mp = (float*)   (ws + 18939904);

    hipLaunchKernelGGL(k_prep,    dim3(64, 4, 8), dim3(256), 0, stream, src_emb, tgt_emb, Qh, Kh);
    hipLaunchKernelGGL(k_yy,      dim3(64, 4),    dim3(256), 0, stream, Kh, yy);
    hipLaunchKernelGGL(k_flash,   dim3(512),      dim3(256), 0, stream, Qh, Kh, yy, tgt, Op, Mp);
    hipLaunchKernelGGL(k_combine, dim3(64),       dim3(256), 0, stream, Op, Mp, out);
}